// Round 1
// baseline (5620.911 us; speedup 1.0000x reference)
//
#include <hip/hip_runtime.h>
#include <hip/hip_bf16.h>
#include <math.h>

#define B_  2
#define T_  2048
#define D_  512
#define H_  8
#define HD_ 64
#define FFN_ 2048
#define VOCAB_ 256
#define BT_ (B_*T_)

// ---------------------------------------------------------------------------
// Embedding + sinusoidal positional concat: x[b,t,:] = [emb[tok], sin, cos]
// ---------------------------------------------------------------------------
__global__ __launch_bounds__(512) void embed_pos_kernel(
    const int* __restrict__ tokens, const float* __restrict__ emb,
    float* __restrict__ x)
{
  int bt = blockIdx.x;          // b*T + t
  int t  = bt & (T_ - 1);
  int j  = threadIdx.x;
  float val;
  if (j < 256) {
    int tok = tokens[bt];
    val = emb[tok * 256 + j];
  } else {
    int jj = (j - 256) & 127;
    // freqs[jj] = exp(-(2*jj)*ln(10000)/256)
    float f = expf(-(float)(2 * jj) * (9.210340371976184f / 256.0f));
    float arg = (float)t * f;
    val = (j < 384) ? sinf(arg) : cosf(arg);
  }
  x[(size_t)bt * D_ + j] = val;
}

// ---------------------------------------------------------------------------
// Generic fp32 GEMM: C[M,N] = act(A[M,K] @ W[K,N] + bias[N])
// 64x64 tile, 256 threads, 4x4 accum per thread, BK=16
// ---------------------------------------------------------------------------
__global__ __launch_bounds__(256) void gemm_kernel(
    const float* __restrict__ A, const float* __restrict__ W,
    const float* __restrict__ bias, float* __restrict__ C,
    int M, int N, int K, int act)
{
  __shared__ float As[16][68];   // [k][m], pad to 68 (16B-aligned rows)
  __shared__ float Bs[16][68];   // [k][n]
  int tid = threadIdx.x;
  int tx = tid & 15, ty = tid >> 4;
  int row0 = blockIdx.y * 64, col0 = blockIdx.x * 64;
  float acc[4][4] = {};
  for (int k0 = 0; k0 < K; k0 += 16) {
#pragma unroll
    for (int i = 0; i < 4; ++i) {
      int idx = tid + i * 256;                 // 0..1023
      int m = idx >> 4, kk = idx & 15;
      As[kk][m] = A[(size_t)(row0 + m) * K + k0 + kk];
      int kb2 = idx >> 6, n = idx & 63;
      Bs[kb2][n] = W[(size_t)(k0 + kb2) * N + col0 + n];
    }
    __syncthreads();
#pragma unroll
    for (int kk = 0; kk < 16; ++kk) {
      float4 a4 = *(const float4*)&As[kk][ty * 4];
      float4 b4 = *(const float4*)&Bs[kk][tx * 4];
      float av[4] = {a4.x, a4.y, a4.z, a4.w};
      float bw[4] = {b4.x, b4.y, b4.z, b4.w};
#pragma unroll
      for (int i = 0; i < 4; ++i)
#pragma unroll
        for (int j = 0; j < 4; ++j)
          acc[i][j] += av[i] * bw[j];
    }
    __syncthreads();
  }
#pragma unroll
  for (int i = 0; i < 4; ++i) {
    int r = row0 + ty * 4 + i;
#pragma unroll
    for (int j = 0; j < 4; ++j) {
      int c = col0 + tx * 4 + j;
      float val = acc[i][j] + bias[c];
      if (act == 1) val = 0.5f * val * (1.0f + erff(val * 0.7071067811865475f));
      C[(size_t)r * N + c] = val;
    }
  }
}

// ---------------------------------------------------------------------------
// FAVOR+ feature map, in-place on [B,T,H,64] rows:
//   xp = x * 64^-0.25 ;  out[m] = exp(xp . rfs[h,:,m] - 0.5*||xp||^2)
// One 64-thread block per (b,t,h) row.
// ---------------------------------------------------------------------------
__global__ __launch_bounds__(64) void favor_kernel(
    float* __restrict__ x, const float* __restrict__ rfs)
{
  int bth = blockIdx.x;           // b*T*H + t*H + h
  int h = bth & (H_ - 1);
  int m = threadIdx.x;
  __shared__ float xp[64];
  size_t off = (size_t)bth * 64;
  xp[m] = x[off + m] * 0.35355339059327373f;   // 64^-0.25
  __syncthreads();
  const float* R = rfs + h * 64 * 64;
  float sq = 0.f, dot = 0.f;
#pragma unroll 8
  for (int dd = 0; dd < 64; ++dd) {
    float xv = xp[dd];
    sq  += xv * xv;
    dot += xv * R[dd * 64 + m];
  }
  x[off + m] = __expf(dot - 0.5f * sq);
}

// ---------------------------------------------------------------------------
// Causal linear-attention scan, one block per (b,h).
// S[m,d] += kf[t,m]*v[t,d]; num[d] = sum_m qf[t,m]*S[m,d];
// z[m] += kf[t,m];           den    = sum_m qf[t,m]*z[m];
// out[t,d] = num[d]/(den+1e-16)
// ---------------------------------------------------------------------------
__global__ __launch_bounds__(256) void attn_scan_kernel(
    const float* __restrict__ qf, const float* __restrict__ kf,
    const float* __restrict__ v, float* __restrict__ out)
{
  int b = blockIdx.x >> 3;
  int h = blockIdx.x & 7;
  int tid = threadIdx.x;
  int d = tid & 63;
  int g = tid >> 6;               // wave index 0..3, owns m in [g*16, g*16+16)
  __shared__ float S[64 * 64];    // S[m*64+d]
  __shared__ float z[64];
  __shared__ float qrow[64], krow[64], vrow[64];
  __shared__ float part[4][64];
  __shared__ float denS;
  for (int i = tid; i < 64 * 64; i += 256) S[i] = 0.f;
  if (tid < 64) z[tid] = 0.f;
  __syncthreads();
  const size_t base = ((size_t)b * T_ * H_ + h) * 64;
  for (int t = 0; t < T_; ++t) {
    size_t off = base + (size_t)t * (H_ * 64);
    if      (tid < 64)  qrow[tid]       = qf[off + tid];
    else if (tid < 128) krow[tid - 64]  = kf[off + tid - 64];
    else if (tid < 192) vrow[tid - 128] = v[off + tid - 128];
    __syncthreads();
    float vd = vrow[d];
    float p = 0.f;
#pragma unroll
    for (int i = 0; i < 16; ++i) {
      int m = g * 16 + i;
      float s = S[m * 64 + d] + krow[m] * vd;
      S[m * 64 + d] = s;
      p += qrow[m] * s;
    }
    part[g][d] = p;
    if (tid < 64) {
      float zz = z[tid] + krow[tid];
      z[tid] = zz;
      float e = qrow[tid] * zz;
      for (int o = 32; o > 0; o >>= 1) e += __shfl_down(e, o, 64);
      if (tid == 0) denS = e;
    }
    __syncthreads();
    if (tid < 64) {
      float num = part[0][tid] + part[1][tid] + part[2][tid] + part[3][tid];
      out[off + tid] = num / (denS + 1e-16f);
    }
    __syncthreads();  // protect shared rows for next t
  }
}

// ---------------------------------------------------------------------------
// x[row,:] += LayerNorm(a[row,:]) * g + b      (rows of 512, 256 threads)
// ---------------------------------------------------------------------------
__global__ __launch_bounds__(256) void ln_add_kernel(
    float* __restrict__ x, const float* __restrict__ a,
    const float* __restrict__ g, const float* __restrict__ bta)
{
  int row = blockIdx.x;
  int tid = threadIdx.x;
  const float* ar = a + (size_t)row * D_;
  float v0 = ar[tid], v1 = ar[tid + 256];
  __shared__ float red[4];
  float w = v0 + v1;
  for (int o = 32; o > 0; o >>= 1) w += __shfl_down(w, o, 64);
  if ((tid & 63) == 0) red[tid >> 6] = w;
  __syncthreads();
  float mu = (red[0] + red[1] + red[2] + red[3]) * (1.f / 512.f);
  float d0 = v0 - mu, d1 = v1 - mu;
  __syncthreads();
  w = d0 * d0 + d1 * d1;
  for (int o = 32; o > 0; o >>= 1) w += __shfl_down(w, o, 64);
  if ((tid & 63) == 0) red[tid >> 6] = w;
  __syncthreads();
  float var = (red[0] + red[1] + red[2] + red[3]) * (1.f / 512.f);
  float rs = rsqrtf(var + 1e-5f);
  size_t xoff = (size_t)row * D_;
  x[xoff + tid]       += d0 * rs * g[tid] + bta[tid];
  x[xoff + tid + 256] += d1 * rs * g[tid + 256] + bta[tid + 256];
}

// ---------------------------------------------------------------------------
extern "C" void kernel_launch(void* const* d_in, const int* in_sizes, int n_in,
                              void* d_out, int out_size, void* d_ws, size_t ws_size,
                              hipStream_t stream) {
  const int*   tokens = (const int*)  d_in[0];
  const float* emb    = (const float*)d_in[1];
  const float* Wq     = (const float*)d_in[2];
  const float* bq     = (const float*)d_in[3];
  const float* Wk     = (const float*)d_in[4];
  const float* bk     = (const float*)d_in[5];
  const float* Wv     = (const float*)d_in[6];
  const float* bv     = (const float*)d_in[7];
  const float* rfs    = (const float*)d_in[8];
  const float* ln1g   = (const float*)d_in[9];
  const float* ln1b   = (const float*)d_in[10];
  const float* ln2g   = (const float*)d_in[11];
  const float* ln2b   = (const float*)d_in[12];
  const float* WU     = (const float*)d_in[13];
  const float* bU     = (const float*)d_in[14];
  const float* WV     = (const float*)d_in[15];
  const float* bV     = (const float*)d_in[16];
  const float* Wout   = (const float*)d_in[17];
  const float* bout   = (const float*)d_in[18];
  float* out = (float*)d_out;

  const size_t R = (size_t)BT_ * D_;          // 2,097,152 floats per region
  float* ws = (float*)d_ws;
  float* x  = ws + 0 * R;
  float* ab = ws + 1 * R;
  float* qb = ws + 2 * R;
  float* kb = ws + 3 * R;
  float* vb = ws + 4 * R;
  float* hb = qb;                             // FFN hidden aliases regions 2..5

  embed_pos_kernel<<<BT_, 512, 0, stream>>>(tokens, emb, x);

  for (int l = 0; l < 2; ++l) {
    dim3 g512(D_ / 64, BT_ / 64);
    gemm_kernel<<<g512, 256, 0, stream>>>(x, Wq + (size_t)l*D_*D_, bq + l*D_, qb, BT_, D_, D_, 0);
    gemm_kernel<<<g512, 256, 0, stream>>>(x, Wk + (size_t)l*D_*D_, bk + l*D_, kb, BT_, D_, D_, 0);
    gemm_kernel<<<g512, 256, 0, stream>>>(x, Wv + (size_t)l*D_*D_, bv + l*D_, vb, BT_, D_, D_, 0);

    const float* rfl = rfs + (size_t)l * H_ * 64 * 64;
    favor_kernel<<<BT_ * H_, 64, 0, stream>>>(qb, rfl);
    favor_kernel<<<BT_ * H_, 64, 0, stream>>>(kb, rfl);

    attn_scan_kernel<<<B_ * H_, 256, 0, stream>>>(qb, kb, vb, ab);

    ln_add_kernel<<<BT_, 256, 0, stream>>>(x, ab, ln1g + l*D_, ln1b + l*D_);

    dim3 gffn1(FFN_ / 64, BT_ / 64);
    gemm_kernel<<<gffn1, 256, 0, stream>>>(x, WU + (size_t)l*D_*FFN_, bU + l*FFN_, hb, BT_, FFN_, D_, 1);
    gemm_kernel<<<g512, 256, 0, stream>>>(hb, WV + (size_t)l*FFN_*D_, bV + l*D_, ab, BT_, D_, FFN_, 0);

    ln_add_kernel<<<BT_, 256, 0, stream>>>(x, ab, ln2g + l*D_, ln2b + l*D_);
  }

  dim3 gout(VOCAB_ / 64, BT_ / 64);
  gemm_kernel<<<gout, 256, 0, stream>>>(x, Wout, bout, out, BT_, VOCAB_, D_, 0);
}

// Round 2
// 1092.243 us; speedup vs baseline: 5.1462x; 5.1462x over previous
//
#include <hip/hip_runtime.h>
#include <hip/hip_bf16.h>
#include <math.h>

#define B_  2
#define T_  2048
#define D_  512
#define H_  8
#define HD_ 64
#define FFN_ 2048
#define VOCAB_ 256
#define BT_ (B_*T_)
#define NC_ 32            // chunks per (b,h), chunk size 64
#define CENT_ 4160        // floats per chunk state: 64*64 S + 64 z

// ---------------------------------------------------------------------------
// Embedding + sinusoidal positional concat: x[b,t,:] = [emb[tok], sin, cos]
// ---------------------------------------------------------------------------
__global__ __launch_bounds__(512) void embed_pos_kernel(
    const int* __restrict__ tokens, const float* __restrict__ emb,
    float* __restrict__ x)
{
  int bt = blockIdx.x;          // b*T + t
  int t  = bt & (T_ - 1);
  int j  = threadIdx.x;
  float val;
  if (j < 256) {
    int tok = tokens[bt];
    val = emb[tok * 256 + j];
  } else {
    int jj = (j - 256) & 127;
    float f = expf(-(float)(2 * jj) * (9.210340371976184f / 256.0f));
    float arg = (float)t * f;
    val = (j < 384) ? sinf(arg) : cosf(arg);
  }
  x[(size_t)bt * D_ + j] = val;
}

// ---------------------------------------------------------------------------
// Generic fp32 GEMM: C[M,N] = act(A[M,K] @ W[K,N] + bias[N])
// ---------------------------------------------------------------------------
__global__ __launch_bounds__(256) void gemm_kernel(
    const float* __restrict__ A, const float* __restrict__ W,
    const float* __restrict__ bias, float* __restrict__ C,
    int M, int N, int K, int act)
{
  __shared__ float As[16][68];
  __shared__ float Bs[16][68];
  int tid = threadIdx.x;
  int tx = tid & 15, ty = tid >> 4;
  int row0 = blockIdx.y * 64, col0 = blockIdx.x * 64;
  float acc[4][4] = {};
  for (int k0 = 0; k0 < K; k0 += 16) {
#pragma unroll
    for (int i = 0; i < 4; ++i) {
      int idx = tid + i * 256;
      int m = idx >> 4, kk = idx & 15;
      As[kk][m] = A[(size_t)(row0 + m) * K + k0 + kk];
      int kb2 = idx >> 6, n = idx & 63;
      Bs[kb2][n] = W[(size_t)(k0 + kb2) * N + col0 + n];
    }
    __syncthreads();
#pragma unroll
    for (int kk = 0; kk < 16; ++kk) {
      float4 a4 = *(const float4*)&As[kk][ty * 4];
      float4 b4 = *(const float4*)&Bs[kk][tx * 4];
      float av[4] = {a4.x, a4.y, a4.z, a4.w};
      float bw[4] = {b4.x, b4.y, b4.z, b4.w};
#pragma unroll
      for (int i = 0; i < 4; ++i)
#pragma unroll
        for (int j = 0; j < 4; ++j)
          acc[i][j] += av[i] * bw[j];
    }
    __syncthreads();
  }
#pragma unroll
  for (int i = 0; i < 4; ++i) {
    int r = row0 + ty * 4 + i;
#pragma unroll
    for (int j = 0; j < 4; ++j) {
      int c = col0 + tx * 4 + j;
      float val = acc[i][j] + bias[c];
      if (act == 1) val = 0.5f * val * (1.0f + erff(val * 0.7071067811865475f));
      C[(size_t)r * N + c] = val;
    }
  }
}

// ---------------------------------------------------------------------------
// FAVOR+ feature map (in place on [B,T,H,64])
// ---------------------------------------------------------------------------
__global__ __launch_bounds__(64) void favor_kernel(
    float* __restrict__ x, const float* __restrict__ rfs)
{
  int bth = blockIdx.x;
  int h = bth & (H_ - 1);
  int m = threadIdx.x;
  __shared__ float xp[64];
  size_t off = (size_t)bth * 64;
  xp[m] = x[off + m] * 0.35355339059327373f;   // 64^-0.25
  __syncthreads();
  const float* R = rfs + h * 64 * 64;
  float sq = 0.f, dot = 0.f;
#pragma unroll 8
  for (int dd = 0; dd < 64; ++dd) {
    float xv = xp[dd];
    sq  += xv * xv;
    dot += xv * R[dd * 64 + m];
  }
  x[off + m] = __expf(dot - 0.5f * sq);
}

// ---------------------------------------------------------------------------
// Pass 1: per-chunk sums. blockIdx.x = bh*31 + c (c = 0..30; last chunk's
// sum is never needed). S[m,d] = sum_t kf[t,m] v[t,d]; z[m] = sum_t kf[t,m]
// ---------------------------------------------------------------------------
__global__ __launch_bounds__(256) void chunk_sum_kernel(
    const float* __restrict__ kf, const float* __restrict__ v,
    float* __restrict__ buf)
{
  int bh = blockIdx.x / 31;
  int c  = blockIdx.x % 31;
  int b = bh >> 3, h = bh & 7;
  __shared__ float Ks[64][68], Vs[64][68];
  int tid = threadIdx.x;
  int d = tid & 63, g = tid >> 6;
  for (int t4 = 0; t4 < 64; t4 += 4) {
    int t = t4 + g;
    size_t off = ((size_t)(b * T_ + c * 64 + t) * D_) + h * 64 + d;
    Ks[t][d] = kf[off];
    Vs[t][d] = v[off];
  }
  __syncthreads();
  float acc[16];
#pragma unroll
  for (int i = 0; i < 16; ++i) acc[i] = 0.f;
  for (int t = 0; t < 64; ++t) {
    float vv = Vs[t][d];
#pragma unroll
    for (int i = 0; i < 16; ++i) acc[i] += Ks[t][g * 16 + i] * vv;
  }
  size_t bo = (size_t)(bh * 31 + c) * CENT_;
#pragma unroll
  for (int i = 0; i < 16; ++i) buf[bo + (size_t)(g * 16 + i) * 64 + d] = acc[i];
  if (tid < 64) {
    float zz = 0.f;
    for (int t = 0; t < 64; ++t) zz += Ks[t][tid];
    buf[bo + 4096 + tid] = zz;
  }
}

// ---------------------------------------------------------------------------
// Pass 2: in-place inclusive scan over the 31 chunk states per (b,h).
// After this, buf[bh][c] = sum of chunks 0..c  (= exclusive prefix for c+1).
// blockIdx.x = bh*17 + egroup
// ---------------------------------------------------------------------------
__global__ __launch_bounds__(256) void chunk_prefix_kernel(float* __restrict__ buf)
{
  int bh = blockIdx.x / 17;
  int grp = blockIdx.x % 17;
  int e = grp * 256 + threadIdx.x;
  if (e >= CENT_) return;
  size_t base = (size_t)bh * 31 * CENT_ + e;
  float run = 0.f;
  for (int c = 0; c < 31; ++c) {
    run += buf[base + (size_t)c * CENT_];
    buf[base + (size_t)c * CENT_] = run;
  }
}

// ---------------------------------------------------------------------------
// Pass 3: per-chunk attention. out = tril(Qf Kf^T) V + Qf S0,
// den = rowsum(tril(A)) + Qf z0. blockIdx.x = bh*32 + c (c = 0..31).
// ---------------------------------------------------------------------------
__global__ __launch_bounds__(256) void chunk_attn_kernel(
    const float* __restrict__ qf, const float* __restrict__ kf,
    const float* __restrict__ v, const float* __restrict__ buf,
    float* __restrict__ out)
{
  int bh = blockIdx.x >> 5;
  int c  = blockIdx.x & 31;
  int b = bh >> 3, h = bh & 7;
  __shared__ float Qs[64][68], Ks[64][68], Vs[64][68];  // Ks reused for A
  __shared__ float den[64];
  int tid = threadIdx.x;
  int d = tid & 63, g = tid >> 6;
  for (int t4 = 0; t4 < 64; t4 += 4) {
    int t = t4 + g;
    size_t off = ((size_t)(b * T_ + c * 64 + t) * D_) + h * 64 + d;
    Qs[t][d] = qf[off];
    Ks[t][d] = kf[off];
    Vs[t][d] = v[off];
  }
  __syncthreads();
  // A[i][j] = sum_m Qs[i][m] Ks[j][m]; thread: i = lane (d), j in g's 16-col band
  float a[16];
  {
    int i = d;
#pragma unroll
    for (int jj = 0; jj < 16; ++jj) a[jj] = 0.f;
    for (int m = 0; m < 64; ++m) {
      float qv = Qs[i][m];
#pragma unroll
      for (int jj = 0; jj < 16; ++jj) a[jj] += qv * Ks[g * 16 + jj][m];
    }
  }
  __syncthreads();           // everyone done reading Ks
  {
    int i = d;
#pragma unroll
    for (int jj = 0; jj < 16; ++jj) {
      int j = g * 16 + jj;
      Ks[i][j] = (j <= i) ? a[jj] : 0.f;   // Ks now holds masked A
    }
  }
  __syncthreads();
  const float* S0 = buf + (size_t)(bh * 31 + (c - 1)) * CENT_;  // valid if c>0
  if (tid < 64) {
    int i = tid;
    float dn = 0.f;
    for (int j = 0; j < 64; ++j) dn += Ks[i][j];
    if (c > 0) {
      const float* z0 = S0 + 4096;
      for (int m = 0; m < 64; ++m) dn += Qs[i][m] * z0[m];
    }
    den[i] = dn;
  }
  // num: thread (g,d) owns rows i = g*16..g*16+15, column d
  float acc[16];
#pragma unroll
  for (int ii = 0; ii < 16; ++ii) acc[ii] = 0.f;
  for (int j = 0; j < 64; ++j) {
    float vv = Vs[j][d];
#pragma unroll
    for (int ii = 0; ii < 16; ++ii) acc[ii] += Ks[g * 16 + ii][j] * vv;
  }
  if (c > 0) {
    for (int m = 0; m < 64; ++m) {
      float s0 = S0[(size_t)m * 64 + d];
#pragma unroll
      for (int ii = 0; ii < 16; ++ii) acc[ii] += Qs[g * 16 + ii][m] * s0;
    }
  }
  __syncthreads();           // den[] visible
#pragma unroll
  for (int ii = 0; ii < 16; ++ii) {
    int i = g * 16 + ii;
    size_t off = ((size_t)(b * T_ + c * 64 + i) * D_) + h * 64 + d;
    out[off] = acc[ii] / (den[i] + 1e-16f);
  }
}

// ---------------------------------------------------------------------------
// x[row,:] += LayerNorm(a[row,:]) * g + b
// ---------------------------------------------------------------------------
__global__ __launch_bounds__(256) void ln_add_kernel(
    float* __restrict__ x, const float* __restrict__ a,
    const float* __restrict__ g, const float* __restrict__ bta)
{
  int row = blockIdx.x;
  int tid = threadIdx.x;
  const float* ar = a + (size_t)row * D_;
  float v0 = ar[tid], v1 = ar[tid + 256];
  __shared__ float red[4];
  float w = v0 + v1;
  for (int o = 32; o > 0; o >>= 1) w += __shfl_down(w, o, 64);
  if ((tid & 63) == 0) red[tid >> 6] = w;
  __syncthreads();
  float mu = (red[0] + red[1] + red[2] + red[3]) * (1.f / 512.f);
  float d0 = v0 - mu, d1 = v1 - mu;
  __syncthreads();
  w = d0 * d0 + d1 * d1;
  for (int o = 32; o > 0; o >>= 1) w += __shfl_down(w, o, 64);
  if ((tid & 63) == 0) red[tid >> 6] = w;
  __syncthreads();
  float var = (red[0] + red[1] + red[2] + red[3]) * (1.f / 512.f);
  float rs = rsqrtf(var + 1e-5f);
  size_t xoff = (size_t)row * D_;
  x[xoff + tid]       += d0 * rs * g[tid] + bta[tid];
  x[xoff + tid + 256] += d1 * rs * g[tid + 256] + bta[tid + 256];
}

// ---------------------------------------------------------------------------
extern "C" void kernel_launch(void* const* d_in, const int* in_sizes, int n_in,
                              void* d_out, int out_size, void* d_ws, size_t ws_size,
                              hipStream_t stream) {
  const int*   tokens = (const int*)  d_in[0];
  const float* emb    = (const float*)d_in[1];
  const float* Wq     = (const float*)d_in[2];
  const float* bq     = (const float*)d_in[3];
  const float* Wk     = (const float*)d_in[4];
  const float* bk     = (const float*)d_in[5];
  const float* Wv     = (const float*)d_in[6];
  const float* bv     = (const float*)d_in[7];
  const float* rfs    = (const float*)d_in[8];
  const float* ln1g   = (const float*)d_in[9];
  const float* ln1b   = (const float*)d_in[10];
  const float* ln2g   = (const float*)d_in[11];
  const float* ln2b   = (const float*)d_in[12];
  const float* WU     = (const float*)d_in[13];
  const float* bU     = (const float*)d_in[14];
  const float* WV     = (const float*)d_in[15];
  const float* bV     = (const float*)d_in[16];
  const float* Wout   = (const float*)d_in[17];
  const float* bout   = (const float*)d_in[18];
  float* out = (float*)d_out;

  const size_t R = (size_t)BT_ * D_;          // 2,097,152 floats per region
  float* ws = (float*)d_ws;
  float* x  = ws + 0 * R;
  float* ab = ws + 1 * R;
  float* qb = ws + 2 * R;
  float* kb = ws + 3 * R;
  float* vb = ws + 4 * R;
  float* sb = ws + 5 * R;                     // chunk-state buffer (7.9 MB)
  float* hb = qb;                             // FFN hidden aliases regions 2..5

  embed_pos_kernel<<<BT_, 512, 0, stream>>>(tokens, emb, x);

  for (int l = 0; l < 2; ++l) {
    dim3 g512(D_ / 64, BT_ / 64);
    gemm_kernel<<<g512, 256, 0, stream>>>(x, Wq + (size_t)l*D_*D_, bq + l*D_, qb, BT_, D_, D_, 0);
    gemm_kernel<<<g512, 256, 0, stream>>>(x, Wk + (size_t)l*D_*D_, bk + l*D_, kb, BT_, D_, D_, 0);
    gemm_kernel<<<g512, 256, 0, stream>>>(x, Wv + (size_t)l*D_*D_, bv + l*D_, vb, BT_, D_, D_, 0);

    const float* rfl = rfs + (size_t)l * H_ * 64 * 64;
    favor_kernel<<<BT_ * H_, 64, 0, stream>>>(qb, rfl);
    favor_kernel<<<BT_ * H_, 64, 0, stream>>>(kb, rfl);

    chunk_sum_kernel<<<16 * 31, 256, 0, stream>>>(kb, vb, sb);
    chunk_prefix_kernel<<<16 * 17, 256, 0, stream>>>(sb);
    chunk_attn_kernel<<<16 * NC_, 256, 0, stream>>>(qb, kb, vb, sb, ab);

    ln_add_kernel<<<BT_, 256, 0, stream>>>(x, ab, ln1g + l*D_, ln1b + l*D_);

    dim3 gffn1(FFN_ / 64, BT_ / 64);
    gemm_kernel<<<gffn1, 256, 0, stream>>>(x, WU + (size_t)l*D_*FFN_, bU + l*FFN_, hb, BT_, FFN_, D_, 1);
    gemm_kernel<<<g512, 256, 0, stream>>>(hb, WV + (size_t)l*FFN_*D_, bV + l*D_, ab, BT_, D_, FFN_, 0);

    ln_add_kernel<<<BT_, 256, 0, stream>>>(x, ab, ln2g + l*D_, ln2b + l*D_);
  }

  dim3 gout(VOCAB_ / 64, BT_ / 64);
  gemm_kernel<<<gout, 256, 0, stream>>>(x, Wout, bout, out, BT_, VOCAB_, D_, 0);
}

// Round 3
// 527.566 us; speedup vs baseline: 10.6544x; 2.0703x over previous
//
#include <hip/hip_runtime.h>
#include <hip/hip_bf16.h>
#include <math.h>

#define B_  2
#define T_  2048
#define D_  512
#define H_  8
#define HD_ 64
#define FFN_ 2048
#define VOCAB_ 256
#define BT_ (B_*T_)
#define NC_ 32            // chunks per (b,h), chunk size 64
#define CENT_ 4160        // floats per chunk state: 64*64 S + 64 z

typedef __attribute__((ext_vector_type(8))) short short8;
typedef __attribute__((ext_vector_type(4))) float float4v;
typedef __hip_bfloat16 bf16;

// ---------------------------------------------------------------------------
// Embedding + sinusoidal positional concat; writes fp32 x and bf16 mirror xb
// ---------------------------------------------------------------------------
__global__ __launch_bounds__(512) void embed_pos_kernel(
    const int* __restrict__ tokens, const float* __restrict__ emb,
    float* __restrict__ x, bf16* __restrict__ xb)
{
  int bt = blockIdx.x;          // b*T + t
  int t  = bt & (T_ - 1);
  int j  = threadIdx.x;
  float val;
  if (j < 256) {
    int tok = tokens[bt];
    val = emb[tok * 256 + j];
  } else {
    int jj = (j - 256) & 127;
    float f = expf(-(float)(2 * jj) * (9.210340371976184f / 256.0f));
    float arg = (float)t * f;
    val = (j < 384) ? sinf(arg) : cosf(arg);
  }
  size_t off = (size_t)bt * D_ + j;
  x[off]  = val;
  xb[off] = __float2bfloat16(val);
}

// ---------------------------------------------------------------------------
// Transpose-cast: W fp32 [K,N] (layer slice via blockIdx.z) -> Wt bf16 [N,K]
// ---------------------------------------------------------------------------
__global__ __launch_bounds__(256) void transpose_cast_kernel(
    const float* __restrict__ W, bf16* __restrict__ Wt, int K, int N)
{
  __shared__ float t[32][33];
  int n0 = blockIdx.x * 32, k0 = blockIdx.y * 32;
  const float* Wl = W + (size_t)blockIdx.z * K * N;
  bf16* Wtl = Wt + (size_t)blockIdx.z * K * N;
  int tx = threadIdx.x & 31, ty = threadIdx.x >> 5;  // ty 0..7
#pragma unroll
  for (int r = 0; r < 4; ++r)
    t[ty + 8 * r][tx] = Wl[(size_t)(k0 + ty + 8 * r) * N + n0 + tx];
  __syncthreads();
#pragma unroll
  for (int r = 0; r < 4; ++r)
    Wtl[(size_t)(n0 + ty + 8 * r) * K + k0 + tx] = __float2bfloat16(t[tx][ty + 8 * r]);
}

// ---------------------------------------------------------------------------
// bf16 MFMA GEMM: C[M,N] = act(A[M,K] @ Bt[N,K]^T + bias[N])
// 128x128 tile, BK=32, 256 threads = 4 waves, each wave 64x64 (4x4 frags).
// mode 0: store fp32. mode 1: gelu, store bf16.
// ---------------------------------------------------------------------------
__global__ __launch_bounds__(256) void gemm_mfma(
    const bf16* __restrict__ A, const bf16* __restrict__ Bt,
    const float* __restrict__ bias, void* __restrict__ Cout,
    int M, int N, int K, int mode)
{
  __shared__ short Al[128 * 32];   // [m][k], k contiguous (8 KB)
  __shared__ short Bl[128 * 32];   // [n][k], k contiguous (8 KB)
  int tid = threadIdx.x;
  int lane = tid & 63, w = tid >> 6;
  int row0 = blockIdx.y * 128, col0 = blockIdx.x * 128;
  int wm = (w >> 1) * 64, wn = (w & 1) * 64;
  int quad = lane >> 4, l16 = lane & 15;
  float4v acc[4][4] = {};

  // staging: each thread owns 16B of rows (tid>>2) and (tid>>2)+64
  int sr = tid >> 2;               // 0..63
  int sk = (tid & 3) * 8;          // 0,8,16,24
  const short* Ag = (const short*)A + (size_t)(row0 + sr) * K + sk;
  const short* Bg = (const short*)Bt + (size_t)(col0 + sr) * K + sk;
  const size_t half = (size_t)64 * K;

  uint4 a0 = *(const uint4*)Ag;
  uint4 a1 = *(const uint4*)(Ag + half);
  uint4 b0 = *(const uint4*)Bg;
  uint4 b1 = *(const uint4*)(Bg + half);

  const int kr = K >> 5;
  for (int kt = 0; kt < kr; ++kt) {
    __syncthreads();               // previous compute done
    *(uint4*)&Al[sr * 32 + sk]        = a0;
    *(uint4*)&Al[(sr + 64) * 32 + sk] = a1;
    *(uint4*)&Bl[sr * 32 + sk]        = b0;
    *(uint4*)&Bl[(sr + 64) * 32 + sk] = b1;
    __syncthreads();
    if (kt + 1 < kr) {             // prefetch next tile (overlaps compute)
      const short* An = Ag + (kt + 1) * 32;
      const short* Bn = Bg + (kt + 1) * 32;
      a0 = *(const uint4*)An;
      a1 = *(const uint4*)(An + half);
      b0 = *(const uint4*)Bn;
      b1 = *(const uint4*)(Bn + half);
    }
    short8 af[4], bf[4];
#pragma unroll
    for (int mi = 0; mi < 4; ++mi)
      af[mi] = *(const short8*)&Al[(wm + mi * 16 + l16) * 32 + quad * 8];
#pragma unroll
    for (int ni = 0; ni < 4; ++ni)
      bf[ni] = *(const short8*)&Bl[(wn + ni * 16 + l16) * 32 + quad * 8];
#pragma unroll
    for (int mi = 0; mi < 4; ++mi)
#pragma unroll
      for (int ni = 0; ni < 4; ++ni)
        acc[mi][ni] = __builtin_amdgcn_mfma_f32_16x16x32_bf16(
            af[mi], bf[ni], acc[mi][ni], 0, 0, 0);
  }

  // epilogue: C[i][j], i = row0+wm+mi*16+quad*4+r, j = col0+wn+ni*16+l16
#pragma unroll
  for (int mi = 0; mi < 4; ++mi) {
#pragma unroll
    for (int ni = 0; ni < 4; ++ni) {
      int j = col0 + wn + ni * 16 + l16;
      float bj = bias[j];
#pragma unroll
      for (int r = 0; r < 4; ++r) {
        int i = row0 + wm + mi * 16 + quad * 4 + r;
        float v = acc[mi][ni][r] + bj;
        if (mode == 1) {
          v = 0.5f * v * (1.0f + erff(v * 0.7071067811865475f));
          ((bf16*)Cout)[(size_t)i * N + j] = __float2bfloat16(v);
        } else {
          ((float*)Cout)[(size_t)i * N + j] = v;
        }
      }
    }
  }
}

// ---------------------------------------------------------------------------
// FAVOR+ feature map (in place on [B,T,H,64] fp32)
// ---------------------------------------------------------------------------
__global__ __launch_bounds__(64) void favor_kernel(
    float* __restrict__ x, const float* __restrict__ rfs)
{
  int bth = blockIdx.x;
  int h = bth & (H_ - 1);
  int m = threadIdx.x;
  __shared__ float xp[64];
  size_t off = (size_t)bth * 64;
  xp[m] = x[off + m] * 0.35355339059327373f;   // 64^-0.25
  __syncthreads();
  const float* R = rfs + h * 64 * 64;
  float sq = 0.f, dot = 0.f;
#pragma unroll 8
  for (int dd = 0; dd < 64; ++dd) {
    float xv = xp[dd];
    sq  += xv * xv;
    dot += xv * R[dd * 64 + m];
  }
  x[off + m] = __expf(dot - 0.5f * sq);
}

// ---------------------------------------------------------------------------
// Pass 1: per-chunk sums (chunks 0..30 per bh)
// ---------------------------------------------------------------------------
__global__ __launch_bounds__(256) void chunk_sum_kernel(
    const float* __restrict__ kf, const float* __restrict__ v,
    float* __restrict__ buf)
{
  int bh = blockIdx.x / 31;
  int c  = blockIdx.x % 31;
  int b = bh >> 3, h = bh & 7;
  __shared__ float Ks[64][68], Vs[64][68];
  int tid = threadIdx.x;
  int d = tid & 63, g = tid >> 6;
  for (int t4 = 0; t4 < 64; t4 += 4) {
    int t = t4 + g;
    size_t off = ((size_t)(b * T_ + c * 64 + t) * D_) + h * 64 + d;
    Ks[t][d] = kf[off];
    Vs[t][d] = v[off];
  }
  __syncthreads();
  float acc[16];
#pragma unroll
  for (int i = 0; i < 16; ++i) acc[i] = 0.f;
  for (int t = 0; t < 64; ++t) {
    float vv = Vs[t][d];
#pragma unroll
    for (int i = 0; i < 16; ++i) acc[i] += Ks[t][g * 16 + i] * vv;
  }
  size_t bo = (size_t)(bh * 31 + c) * CENT_;
#pragma unroll
  for (int i = 0; i < 16; ++i) buf[bo + (size_t)(g * 16 + i) * 64 + d] = acc[i];
  if (tid < 64) {
    float zz = 0.f;
    for (int t = 0; t < 64; ++t) zz += Ks[t][tid];
    buf[bo + 4096 + tid] = zz;
  }
}

// ---------------------------------------------------------------------------
// Pass 2: inclusive scan over 31 chunk states per (b,h)
// ---------------------------------------------------------------------------
__global__ __launch_bounds__(256) void chunk_prefix_kernel(float* __restrict__ buf)
{
  int bh = blockIdx.x / 17;
  int grp = blockIdx.x % 17;
  int e = grp * 256 + threadIdx.x;
  if (e >= CENT_) return;
  size_t base = (size_t)bh * 31 * CENT_ + e;
  float run = 0.f;
  for (int c = 0; c < 31; ++c) {
    run += buf[base + (size_t)c * CENT_];
    buf[base + (size_t)c * CENT_] = run;
  }
}

// ---------------------------------------------------------------------------
// Pass 3: per-chunk attention
// ---------------------------------------------------------------------------
__global__ __launch_bounds__(256) void chunk_attn_kernel(
    const float* __restrict__ qf, const float* __restrict__ kf,
    const float* __restrict__ v, const float* __restrict__ buf,
    float* __restrict__ out)
{
  int bh = blockIdx.x >> 5;
  int c  = blockIdx.x & 31;
  int b = bh >> 3, h = bh & 7;
  __shared__ float Qs[64][68], Ks[64][68], Vs[64][68];  // Ks reused for A
  __shared__ float den[64];
  int tid = threadIdx.x;
  int d = tid & 63, g = tid >> 6;
  for (int t4 = 0; t4 < 64; t4 += 4) {
    int t = t4 + g;
    size_t off = ((size_t)(b * T_ + c * 64 + t) * D_) + h * 64 + d;
    Qs[t][d] = qf[off];
    Ks[t][d] = kf[off];
    Vs[t][d] = v[off];
  }
  __syncthreads();
  float a[16];
  {
    int i = d;
#pragma unroll
    for (int jj = 0; jj < 16; ++jj) a[jj] = 0.f;
    for (int m = 0; m < 64; ++m) {
      float qv = Qs[i][m];
#pragma unroll
      for (int jj = 0; jj < 16; ++jj) a[jj] += qv * Ks[g * 16 + jj][m];
    }
  }
  __syncthreads();
  {
    int i = d;
#pragma unroll
    for (int jj = 0; jj < 16; ++jj) {
      int j = g * 16 + jj;
      Ks[i][j] = (j <= i) ? a[jj] : 0.f;
    }
  }
  __syncthreads();
  const float* S0 = buf + (size_t)(bh * 31 + (c - 1)) * CENT_;  // valid if c>0
  if (tid < 64) {
    int i = tid;
    float dn = 0.f;
    for (int j = 0; j < 64; ++j) dn += Ks[i][j];
    if (c > 0) {
      const float* z0 = S0 + 4096;
      for (int m = 0; m < 64; ++m) dn += Qs[i][m] * z0[m];
    }
    den[i] = dn;
  }
  float acc[16];
#pragma unroll
  for (int ii = 0; ii < 16; ++ii) acc[ii] = 0.f;
  for (int j = 0; j < 64; ++j) {
    float vv = Vs[j][d];
#pragma unroll
    for (int ii = 0; ii < 16; ++ii) acc[ii] += Ks[g * 16 + ii][j] * vv;
  }
  if (c > 0) {
    for (int m = 0; m < 64; ++m) {
      float s0 = S0[(size_t)m * 64 + d];
#pragma unroll
      for (int ii = 0; ii < 16; ++ii) acc[ii] += Qs[g * 16 + ii][m] * s0;
    }
  }
  __syncthreads();
#pragma unroll
  for (int ii = 0; ii < 16; ++ii) {
    int i = g * 16 + ii;
    size_t off = ((size_t)(b * T_ + c * 64 + i) * D_) + h * 64 + d;
    out[off] = acc[ii] / (den[i] + 1e-16f);
  }
}

// ---------------------------------------------------------------------------
// x[row,:] += LayerNorm(a[row,:]) * g + b ; also writes bf16 mirror xb
// ---------------------------------------------------------------------------
__global__ __launch_bounds__(256) void ln_add_kernel(
    float* __restrict__ x, bf16* __restrict__ xb, const float* __restrict__ a,
    const float* __restrict__ g, const float* __restrict__ bta)
{
  int row = blockIdx.x;
  int tid = threadIdx.x;
  const float* ar = a + (size_t)row * D_;
  float v0 = ar[tid], v1 = ar[tid + 256];
  __shared__ float red[4];
  float w = v0 + v1;
  for (int o = 32; o > 0; o >>= 1) w += __shfl_down(w, o, 64);
  if ((tid & 63) == 0) red[tid >> 6] = w;
  __syncthreads();
  float mu = (red[0] + red[1] + red[2] + red[3]) * (1.f / 512.f);
  float d0 = v0 - mu, d1 = v1 - mu;
  __syncthreads();
  w = d0 * d0 + d1 * d1;
  for (int o = 32; o > 0; o >>= 1) w += __shfl_down(w, o, 64);
  if ((tid & 63) == 0) red[tid >> 6] = w;
  __syncthreads();
  float var = (red[0] + red[1] + red[2] + red[3]) * (1.f / 512.f);
  float rs = rsqrtf(var + 1e-5f);
  size_t xoff = (size_t)row * D_;
  float n0 = x[xoff + tid]       + d0 * rs * g[tid]       + bta[tid];
  float n1 = x[xoff + tid + 256] + d1 * rs * g[tid + 256] + bta[tid + 256];
  x[xoff + tid]        = n0;
  x[xoff + tid + 256]  = n1;
  xb[xoff + tid]       = __float2bfloat16(n0);
  xb[xoff + tid + 256] = __float2bfloat16(n1);
}

// ---------------------------------------------------------------------------
extern "C" void kernel_launch(void* const* d_in, const int* in_sizes, int n_in,
                              void* d_out, int out_size, void* d_ws, size_t ws_size,
                              hipStream_t stream) {
  const int*   tokens = (const int*)  d_in[0];
  const float* emb    = (const float*)d_in[1];
  const float* Wq     = (const float*)d_in[2];
  const float* bq     = (const float*)d_in[3];
  const float* Wk     = (const float*)d_in[4];
  const float* bk     = (const float*)d_in[5];
  const float* Wv     = (const float*)d_in[6];
  const float* bv     = (const float*)d_in[7];
  const float* rfs    = (const float*)d_in[8];
  const float* ln1g   = (const float*)d_in[9];
  const float* ln1b   = (const float*)d_in[10];
  const float* ln2g   = (const float*)d_in[11];
  const float* ln2b   = (const float*)d_in[12];
  const float* WU     = (const float*)d_in[13];
  const float* bU     = (const float*)d_in[14];
  const float* WV     = (const float*)d_in[15];
  const float* bV     = (const float*)d_in[16];
  const float* Wout   = (const float*)d_in[17];
  const float* bout   = (const float*)d_in[18];
  float* out = (float*)d_out;

  const size_t R = (size_t)BT_ * D_;          // 2,097,152 floats (8 MB)
  float* ws = (float*)d_ws;
  float* x  = ws + 0 * R;
  float* ab = ws + 1 * R;
  float* qb = ws + 2 * R;
  float* kb = ws + 3 * R;
  float* vb = ws + 4 * R;
  float* sb = ws + 5 * R;                     // chunk states (7.9 MB)
  bf16*  xb = (bf16*)(ws + 6 * R);            // R bf16 = 4 MB
  bf16*  hb = (bf16*)qb;                      // FFN hidden bf16 aliases qb+kb
  // transposed bf16 weights
  bf16* wT    = (bf16*)(ws + 6 * R + R / 2);
  bf16* WqT   = wT;                            // [L][D][D]
  bf16* WkT   = WqT + (size_t)2 * D_ * D_;
  bf16* WvT   = WkT + (size_t)2 * D_ * D_;
  bf16* WUT   = WvT + (size_t)2 * D_ * D_;     // [L][FFN][D]
  bf16* WVT   = WUT + (size_t)2 * D_ * FFN_;   // [L][D][FFN]
  bf16* WoutT = WVT + (size_t)2 * D_ * FFN_;   // [VOCAB][D]

  // ---- weight transpose-casts ----
  transpose_cast_kernel<<<dim3(D_/32,  D_/32,  2), 256, 0, stream>>>(Wq,   WqT,   D_,   D_);
  transpose_cast_kernel<<<dim3(D_/32,  D_/32,  2), 256, 0, stream>>>(Wk,   WkT,   D_,   D_);
  transpose_cast_kernel<<<dim3(D_/32,  D_/32,  2), 256, 0, stream>>>(Wv,   WvT,   D_,   D_);
  transpose_cast_kernel<<<dim3(FFN_/32,D_/32,  2), 256, 0, stream>>>(WU,   WUT,   D_,   FFN_);
  transpose_cast_kernel<<<dim3(D_/32,  FFN_/32,2), 256, 0, stream>>>(WV,   WVT,   FFN_, D_);
  transpose_cast_kernel<<<dim3(VOCAB_/32, D_/32,1), 256, 0, stream>>>(Wout, WoutT, D_,  VOCAB_);

  embed_pos_kernel<<<BT_, 512, 0, stream>>>(tokens, emb, x, xb);

  for (int l = 0; l < 2; ++l) {
    dim3 gq(D_ / 128, BT_ / 128);
    gemm_mfma<<<gq, 256, 0, stream>>>(xb, WqT + (size_t)l*D_*D_, bq + l*D_, qb, BT_, D_, D_, 0);
    gemm_mfma<<<gq, 256, 0, stream>>>(xb, WkT + (size_t)l*D_*D_, bk + l*D_, kb, BT_, D_, D_, 0);
    gemm_mfma<<<gq, 256, 0, stream>>>(xb, WvT + (size_t)l*D_*D_, bv + l*D_, vb, BT_, D_, D_, 0);

    const float* rfl = rfs + (size_t)l * H_ * 64 * 64;
    favor_kernel<<<BT_ * H_, 64, 0, stream>>>(qb, rfl);
    favor_kernel<<<BT_ * H_, 64, 0, stream>>>(kb, rfl);

    chunk_sum_kernel<<<16 * 31, 256, 0, stream>>>(kb, vb, sb);
    chunk_prefix_kernel<<<16 * 17, 256, 0, stream>>>(sb);
    chunk_attn_kernel<<<16 * NC_, 256, 0, stream>>>(qb, kb, vb, sb, ab);

    ln_add_kernel<<<BT_, 256, 0, stream>>>(x, xb, ab, ln1g + l*D_, ln1b + l*D_);

    dim3 gffn1(FFN_ / 128, BT_ / 128);
    gemm_mfma<<<gffn1, 256, 0, stream>>>(xb, WUT + (size_t)l*D_*FFN_, bU + l*FFN_, hb, BT_, FFN_, D_, 1);
    dim3 gffn2(D_ / 128, BT_ / 128);
    gemm_mfma<<<gffn2, 256, 0, stream>>>(hb, WVT + (size_t)l*FFN_*D_, bV + l*D_, ab, BT_, D_, FFN_, 0);

    ln_add_kernel<<<BT_, 256, 0, stream>>>(x, xb, ab, ln2g + l*D_, ln2b + l*D_);
  }

  dim3 gout(VOCAB_ / 128, BT_ / 128);
  gemm_mfma<<<gout, 256, 0, stream>>>(xb, WoutT, bout, out, BT_, VOCAB_, D_, 0);
}